// Round 9
// baseline (30055.853 us; speedup 1.0000x reference)
//
#include <hip/hip_runtime.h>
#include <stdint.h>

#define NN 4096      // nodes / steps
#define DD 256       // hidden dim
#define NWG 64       // workgroups
#define TT 256       // threads per WG
#define ROWS 64      // NN/NWG rows per WG
#define GR 16        // gate rows per WG (1024/NWG)
#define NSTEPS 4096
#define GUARD (1u << 20)

typedef float f32x4 __attribute__((ext_vector_type(4)));
typedef float f32x2 __attribute__((ext_vector_type(2)));

// ---------------- workspace layout (bytes) ----------------
#define OFF_HDR      0u          // 64 x 8B: {u32 tag, f32 ps} packed
#define OFF_QS       4096u       // 64 x 128B: lineA {tag,q0,q1,q2} @+0, lineB {tag,q3,-,-} @+64
#define OFF_SCAL     12288u      // [0]=maxHpNorm bits, [1]=ebBound bits
#define OFF_PR       12352u      // 64*256 f32 partial r-tilde
#define OFF_EB       77888u      // 4096 f32  (h @ b_a)
#define OFF_BPACK    94272u      // 1024 f32 packed bias
#define OFF_WPACK    98368u      // 1024*512 f32 packed gate weights (+2097152)
#define OFF_HPB      2195520u    // 4096*256 bf16 packed [wg][k4][row] (Hp) (+2097152)
#define OFF_HP2      4292672u    // paired-row h bf16: [wg][r2:32][col:256] uint (+2097152)
// total 6,389,824 B

// ---------------- LDS layout ----------------
#define S_HPL    0u        // 32768  uint2 [k4:64][row:64]
#define S_HP     32768u    // 32768  uint  [r2:32][col:256]
#define S_WL     65536u    // 33280  f32   [16][520]
#define S_QRL    98816u    // 2048   f32   [512] : q | r
#define S_PRL    100864u   // 4096   f32   [4][256] combine partials
#define S_RACC   104960u   // 1088   f32   publish staging
#define S_EL     106048u   // 1024   f32   [4][64]
#define S_PL     107072u   // 256    f32   [64]
#define S_GL     107328u   // 64     f32   [16]
#define S_CLS    107392u   // 16     f32   [4]
#define S_RED4   107408u   // 16
#define S_SL     107424u   // 16
#define S_EBL    107440u   // 256    f32   [64]
#define S_QL4    107696u   // 16     f32   [4]
#define SMEM_BYTES 107712

__device__ __forceinline__ float bf2f(unsigned short u) {
  return __uint_as_float(((unsigned)u) << 16);
}
__device__ __forceinline__ unsigned short f2bf(float f) {
  unsigned x = __float_as_uint(f);
  unsigned r = x + 0x7fffu + ((x >> 16) & 1u);
  return (unsigned short)(r >> 16);
}

// ---- coherent-bypass memory ops (sc0 sc1: skip L1/L2, device-coherent) ----
__device__ __forceinline__ f32x4 ld_v4(const void* p) {
  f32x4 v;
  asm volatile("global_load_dwordx4 %0, %1, off sc0 sc1\n\ts_waitcnt vmcnt(0)"
               : "=v"(v) : "v"(p) : "memory");
  return v;
}
__device__ __forceinline__ f32x4 ld_v4_async(const void* p) {
  f32x4 v;
  asm volatile("global_load_dwordx4 %0, %1, off sc0 sc1" : "=v"(v) : "v"(p) : "memory");
  return v;
}
__device__ __forceinline__ f32x2 ld_v2(const void* p) {
  f32x2 v;
  asm volatile("global_load_dwordx2 %0, %1, off sc0 sc1\n\ts_waitcnt vmcnt(0)"
               : "=v"(v) : "v"(p) : "memory");
  return v;
}
__device__ __forceinline__ void st_v4(void* p, f32x4 v) {
  asm volatile("global_store_dwordx4 %0, %1, off sc0 sc1" :: "v"(p), "v"(v) : "memory");
}
__device__ __forceinline__ void st_v2(void* p, f32x2 v) {
  asm volatile("global_store_dwordx2 %0, %1, off sc0 sc1" :: "v"(p), "v"(v) : "memory");
}
__device__ __forceinline__ void vmdrain() {
  asm volatile("s_waitcnt vmcnt(0)" ::: "memory");
}
__device__ __forceinline__ void npause() { __builtin_amdgcn_s_sleep(1); }

// ---------------- K0: init dynamic state ----------------
__global__ void k0_init(char* ws) {
  int t = threadIdx.x;
  unsigned* u = (unsigned*)ws;
  float* f = (float*)ws;
  for (int i = t; i < 64; i += TT) {       // packed 8B headers
    u[(OFF_HDR >> 2) + i * 2] = 0u;
    f[(OFF_HDR >> 2) + i * 2 + 1] = 1.0f / NWG;
  }
  for (int i = t; i < 64; i += TT) {
    u[(OFF_QS >> 2) + i * 32] = 0u;
    u[(OFF_QS >> 2) + i * 32 + 16] = 0u;
  }
  if (t == 0) { u[OFF_SCAL / 4] = 0u; u[OFF_SCAL / 4 + 1] = 0u; }
  for (int i = t; i < 64 * 256; i += TT) f[(OFF_PR >> 2) + i] = 0.f;
}

// ---------------- K1: Hp = h @ W_a (bf16, packed), eb = h @ b_a, bounds ----------------
__global__ __launch_bounds__(256) void k1_hp(const float* __restrict__ h,
                                             const float* __restrict__ W_a,
                                             const float* __restrict__ b_a,
                                             char* ws) {
  __shared__ float hL1[16][256];
  __shared__ float scr[16][256];
  __shared__ float redN[4][16];
  __shared__ float redE[4][16];
  const int t = threadIdx.x, b = blockIdx.x;
  const int i0 = b * 16;
  for (int i = t; i < 16 * 256; i += 256) hL1[i >> 8][i & 255] = h[i0 * 256 + i];
  __syncthreads();
  float acc[16];
#pragma unroll
  for (int ii = 0; ii < 16; ++ii) acc[ii] = 0.f;
  for (int j = 0; j < 256; ++j) {
    float wa = W_a[j * 256 + t];
#pragma unroll
    for (int ii = 0; ii < 16; ++ii) acc[ii] += hL1[ii][j] * wa;
  }
#pragma unroll
  for (int ii = 0; ii < 16; ++ii) scr[ii][t] = acc[ii];
  const int lane = t & 63, wv = t >> 6;
  const float ba = b_a[t];
  for (int ii = 0; ii < 16; ++ii) {
    float a2 = acc[ii] * acc[ii];
    float eb = hL1[ii][t] * ba;
    for (int m = 32; m; m >>= 1) { a2 += __shfl_xor(a2, m); eb += __shfl_xor(eb, m); }
    if (lane == 0) { redN[wv][ii] = a2; redE[wv][ii] = eb; }
  }
  __syncthreads();
  unsigned* scal = (unsigned*)(ws + OFF_SCAL);
  float* ebg = (float*)(ws + OFF_EB);
  if (t < 16) {
    float n2 = redN[0][t] + redN[1][t] + redN[2][t] + redN[3][t];
    float ebv = redE[0][t] + redE[1][t] + redE[2][t] + redE[3][t];
    ebg[i0 + t] = ebv;
    atomicMax(scal + 0, __float_as_uint(sqrtf(n2)));
    atomicMax(scal + 1, __float_as_uint(fabsf(ebv)));
  }
  uint2* hpB = (uint2*)(ws + OFF_HPB);
  const int wq = b >> 2, sub = b & 3;
  for (int idx = t; idx < 16 * 64; idx += 256) {
    int ii = idx >> 6, k4 = idx & 63;
    unsigned short u0 = f2bf(scr[ii][4 * k4 + 0]);
    unsigned short u1 = f2bf(scr[ii][4 * k4 + 1]);
    unsigned short u2 = f2bf(scr[ii][4 * k4 + 2]);
    unsigned short u3 = f2bf(scr[ii][4 * k4 + 3]);
    uint2 pv;
    pv.x = (unsigned)u0 | ((unsigned)u1 << 16);
    pv.y = (unsigned)u2 | ((unsigned)u3 << 16);
    int rl = sub * 16 + ii;
    hpB[wq * 4096 + k4 * 64 + rl] = pv;
  }
}

// ---------------- K2: pack paired h (bf16), fold gate weights/bias ----------------
__global__ void k2_pack(const float* __restrict__ h, const float* __restrict__ W_ih,
                        const float* __restrict__ W_hh, const float* __restrict__ b_ih,
                        const float* __restrict__ b_hh, char* ws) {
  unsigned* hp2 = (unsigned*)(ws + OFF_HP2);
  float* wpack = (float*)(ws + OFF_WPACK);
  float* bpack = (float*)(ws + OFF_BPACK);
  int idx0 = blockIdx.x * blockDim.x + threadIdx.x;
  int stride = gridDim.x * blockDim.x;
  for (int i = idx0; i < NN * DD / 2; i += stride) {
    int col = i & 255;
    int r2 = (i >> 8) & 31;
    int w = i >> 13;
    int row0 = (w * 64 + 2 * r2) * 256 + col;
    hp2[i] = (unsigned)f2bf(h[row0]) | ((unsigned)f2bf(h[row0 + 256]) << 16);
  }
  for (int i = idx0; i < 1024 * 512; i += stride) {
    int row = i >> 9, c = i & 511;
    int g = row >> 8, d = row & 255;
    int wq = d >> 2, dl = d & 3;
    float v = W_ih[row * 512 + c];
    if (c < 256) v += W_hh[row * 256 + c];
    wpack[(wq * GR + g * 4 + dl) * 512 + c] = v;
  }
  for (int i = idx0; i < 1024; i += stride) {
    int g = i >> 8, d = i & 255, wq = d >> 2, dl = d & 3;
    bpack[wq * GR + g * 4 + dl] = b_ih[i] + b_hh[i];
  }
}

// ---------------- main persistent kernel ----------------
__global__ __launch_bounds__(TT, 1) void s2s_main(char* __restrict__ ws,
                                                  float* __restrict__ out) {
  extern __shared__ char smem[];
  uint2* HpL = (uint2*)(smem + S_HPL);
  unsigned* hP = (unsigned*)(smem + S_HP);
  float* wL = (float*)(smem + S_WL);
  float* qrL = (float*)(smem + S_QRL);
  float* prL = (float*)(smem + S_PRL);
  float* rAcc = (float*)(smem + S_RACC);
  float* eL = (float*)(smem + S_EL);
  float* pL = (float*)(smem + S_PL);
  float* gL = (float*)(smem + S_GL);
  float* cLs = (float*)(smem + S_CLS);
  float* red4 = (float*)(smem + S_RED4);
  float* ebL = (float*)(smem + S_EBL);
  float* qL4 = (float*)(smem + S_QL4);

  const int w = blockIdx.x, tid = threadIdx.x;
  char* hdrBase = ws + OFF_HDR;
  char* qsBase = ws + OFF_QS;
  const unsigned* scal = (const unsigned*)(ws + OFF_SCAL);
  float* pr = (float*)(ws + OFF_PR);
  const float* ebg = (const float*)(ws + OFF_EB);
  const float* bpack = (const float*)(ws + OFF_BPACK);
  const float* wpack = (const float*)(ws + OFF_WPACK);
  const uint2* hpB = (const uint2*)(ws + OFF_HPB) + (size_t)w * 4096;
  const unsigned* hp2 = (const unsigned*)(ws + OFF_HP2) + (size_t)w * 8192;

  for (int i = tid; i < 4096; i += TT) HpL[i] = hpB[i];
  for (int i = tid; i < 8192; i += TT) hP[i] = hp2[i];
  for (int i = tid; i < 8192; i += TT) {
    int r = i >> 9, c = i & 511;
    wL[r * 520 + c] = wpack[(size_t)w * 8192 + i];
  }
  if (tid < 64) ebL[tid] = ebg[w * 64 + tid];
  if (tid < 4) cLs[tid] = 0.f;
  qrL[tid] = 0.f;
  qrL[256 + tid] = 0.f;
  const float maxHpN = __uint_as_float(scal[0]);
  const float ebB = __uint_as_float(scal[1]);
  __syncthreads();

  const int gr_lr = tid >> 4, gr_li = tid & 15;
  const float* wrow = wL + gr_lr * 520;
  const float brow = bpack[w * GR + gr_lr];
  const int wv4 = tid >> 6, l = tid & 63;
  float psW = 0.f;   // valid in tid 0 only
  float acc = 0.f;   // Wq @ q_{t-1}, carried from previous phase B (q_{-1}=0)

  for (int t = 0; t < NSTEPS; ++t) {
    // ==== phase A: q_t = LSTM(q_{t-1}, r_{t-1}) ====
    // per-wave poll of all 64 packed headers (lane = slice); no cross-wave barrier
    float psTot;
    {
      const char* hp = hdrBase + l * 8;
      f32x2 hv = ld_v2(hp);               // fast path: no sleep
      unsigned guard = 0;
      while (__float_as_uint(hv.x) < (unsigned)t && ++guard <= GUARD) {
        npause();
        hv = ld_v2(hp);
      }
      float s = hv.y;
#pragma unroll
      for (int m = 32; m; m >>= 1) s += __shfl_xor(s, m);
      psTot = fmaxf(s, 1e-35f);           // every lane of every wave holds ps
    }
    // bulk read issued immediately per-wave (wave verified all 64 headers)
    {
      f32x4 tv[16];
#pragma unroll
      for (int i = 0; i < 16; ++i) {
        int v = (wv4 * 16 + i + w) & 63;
        tv[i] = ld_v4_async(pr + v * 256 + (l << 2));
      }
      vmdrain();
      __builtin_amdgcn_sched_barrier(0);
      float rx = 0.f, ry = 0.f, rz = 0.f, rw = 0.f;
#pragma unroll
      for (int i = 0; i < 16; ++i) { rx += tv[i].x; ry += tv[i].y; rz += tv[i].z; rw += tv[i].w; }
      float* d = prL + wv4 * 256 + (l << 2);
      d[0] = rx; d[1] = ry; d[2] = rz; d[3] = rw;
    }
    __syncthreads();
    {
      float rsum = prL[tid] + prL[256 + tid] + prL[512 + tid] + prL[768 + tid];
      qrL[256 + tid] = rsum / psTot;  // r_{t-1}
    }
    __syncthreads();
    // Wr @ r (Wq @ q_{t-1} already in carried acc)
#pragma unroll
    for (int j = 4; j < 8; ++j) {
      int c0 = gr_li * 4 + j * 64;
      const float4 wv = *(const float4*)(wrow + c0);
      const float4 qv = *(const float4*)(qrL + c0);
      acc += wv.x * qv.x + wv.y * qv.y + wv.z * qv.z + wv.w * qv.w;
    }
    acc += __shfl_xor(acc, 8);
    acc += __shfl_xor(acc, 4);
    acc += __shfl_xor(acc, 2);
    acc += __shfl_xor(acc, 1);
    if (gr_li == 0) gL[gr_lr] = acc + brow;
    __syncthreads();
    if (tid < 4) {
      float gi = gL[tid], gf = gL[4 + tid], gg = gL[8 + tid], go = gL[12 + tid];
      float co = cLs[tid];
      float si = 1.f / (1.f + __expf(-gi));
      float sf = 1.f / (1.f + __expf(-gf));
      float so = 1.f / (1.f + __expf(-go));
      float cn = sf * co + si * tanhf(gg);
      cLs[tid] = cn;
      qL4[tid] = so * tanhf(cn);
    }
    // qL4 written by wave 0, read by wave 0 -> same-wave LDS order
    if (tid < 2) {
      float4 q4 = *(const float4*)qL4;
      f32x4 line;
      line.x = __uint_as_float((unsigned)(t + 1));
      if (tid == 0) { line.y = q4.x; line.z = q4.y; line.w = q4.z; }
      else          { line.y = q4.w; line.z = 0.f;  line.w = 0.f; }
      st_v4(qsBase + w * 128 + tid * 64, line);  // self-validating, no drain
    }

    // ==== phase B: e = Hp q + eb, partials ====
    float nr = 0.f;
    if (l < 32) {
      const int w2 = (wv4 << 4) + (l >> 1);
      const char* qp = qsBase + w2 * 128 + (l & 1) * 64;
      const unsigned need = (unsigned)(t + 1);
      f32x4 qv = ld_v4(qp);               // fast path: no sleep
      unsigned guard = 0;
      while (__float_as_uint(qv.x) < need && ++guard <= GUARD) {
        npause();
        qv = ld_v4(qp);
      }
      if ((l & 1) == 0) {
        qrL[4 * w2] = qv.y; qrL[4 * w2 + 1] = qv.z; qrL[4 * w2 + 2] = qv.w;
        nr = qv.y * qv.y + qv.z * qv.z + qv.w * qv.w;
      } else {
        qrL[4 * w2 + 3] = qv.y;
        nr = qv.y * qv.y;
      }
    }
#pragma unroll
    for (int m = 1; m < 64; m <<= 1) nr += __shfl_xor(nr, m);
    if (l == 0) red4[wv4] = nr;
    // e partial on own quarter (qrL quarter written by this wave)
    f32x4 qk[16];
#pragma unroll
    for (int j = 0; j < 16; ++j)
      qk[j] = *(const f32x4*)(qrL + (wv4 << 6) + (j << 2));
    float eacc = 0.f;
#pragma unroll
    for (int j = 0; j < 16; ++j) {
      const uint2 hp = HpL[(((wv4 << 4) + j) << 6) + l];
      eacc += bf2f((unsigned short)(hp.x)) * qk[j].x +
              bf2f((unsigned short)(hp.x >> 16)) * qk[j].y +
              bf2f((unsigned short)(hp.y)) * qk[j].z +
              bf2f((unsigned short)(hp.y >> 16)) * qk[j].w;
    }
    eL[(wv4 << 6) + l] = eacc;
    __syncthreads();
    if (tid < 64) {
      const float qnorm = sqrtf(red4[0] + red4[1] + red4[2] + red4[3]);
      const float Mhat = 0.5f * maxHpN * qnorm + ebB;
      float e = eL[tid] + eL[64 + tid] + eL[128 + tid] + eL[192 + tid] + ebL[tid];
      float p = __expf(fminf(e - Mhat, 60.f));
      pL[tid] = p;
      float sv = p;
#pragma unroll
      for (int m = 32; m; m >>= 1) sv += __shfl_xor(sv, m);
      if (tid == 0) psW = sv;
    }
    __syncthreads();
    // r partial over 32 paired rows
    float r2 = 0.f;
#pragma unroll
    for (int r2i = 0; r2i < 32; ++r2i) {
      const unsigned hv = hP[(r2i << 8) + tid];
      r2 += pL[2 * r2i] * bf2f((unsigned short)hv) +
            pL[2 * r2i + 1] * bf2f((unsigned short)(hv >> 16));
    }
    rAcc[tid] = r2;
    __syncthreads();
    // wave 0 issues coalesced pr stores (no drain yet)
    if (tid < 64) {
      f32x4 pv;
      pv.x = rAcc[4 * tid]; pv.y = rAcc[4 * tid + 1];
      pv.z = rAcc[4 * tid + 2]; pv.w = rAcc[4 * tid + 3];
      st_v4(pr + (w << 8) + (tid << 2), pv);
    }
    // drain-shadow: compute next step's Wq @ q_t while store-acks are in flight
    {
      float accN = 0.f;
#pragma unroll
      for (int j = 0; j < 4; ++j) {
        int c0 = gr_li * 4 + j * 64;
        const float4 wv = *(const float4*)(wrow + c0);
        const float4 qv = *(const float4*)(qrL + c0);
        accN += wv.x * qv.x + wv.y * qv.y + wv.z * qv.z + wv.w * qv.w;
      }
      if (tid < 64) vmdrain();    // wave 0 drains its own partial stores
      __syncthreads();            // all waves see completion
      if (tid == 0) {
        f32x2 hv2;
        hv2.x = __uint_as_float((unsigned)(t + 1));
        hv2.y = psW;
        st_v2(hdrBase + w * 8, hv2);
      }
      acc = accN;
    }
  }

  // ==== epilogue: q_star = [q_final, r_final] (WG 0 only) ====
  if (w == 0) {
    float psTot;
    {
      const char* hp = hdrBase + l * 8;
      f32x2 hv = ld_v2(hp);
      unsigned guard = 0;
      while (__float_as_uint(hv.x) < (unsigned)NSTEPS && ++guard <= GUARD) {
        npause();
        hv = ld_v2(hp);
      }
      float s = hv.y;
#pragma unroll
      for (int m = 32; m; m >>= 1) s += __shfl_xor(s, m);
      psTot = fmaxf(s, 1e-35f);
    }
    {
      f32x4 tv[16];
#pragma unroll
      for (int i = 0; i < 16; ++i) {
        int v = (wv4 * 16 + i) & 63;
        tv[i] = ld_v4_async(pr + v * 256 + (l << 2));
      }
      vmdrain();
      __builtin_amdgcn_sched_barrier(0);
      float rx = 0.f, ry = 0.f, rz = 0.f, rw = 0.f;
#pragma unroll
      for (int i = 0; i < 16; ++i) { rx += tv[i].x; ry += tv[i].y; rz += tv[i].z; rw += tv[i].w; }
      float* d = prL + wv4 * 256 + (l << 2);
      d[0] = rx; d[1] = ry; d[2] = rz; d[3] = rw;
    }
    __syncthreads();
    float rsum = prL[tid] + prL[256 + tid] + prL[512 + tid] + prL[768 + tid];
    out[tid] = qrL[tid];             // q_final (phase B kept q in qrL)
    out[256 + tid] = rsum / psTot;   // r_final
  }
}

extern "C" void kernel_launch(void* const* d_in, const int* in_sizes, int n_in,
                              void* d_out, int out_size, void* d_ws, size_t ws_size,
                              hipStream_t stream) {
  const float* h = (const float*)d_in[0];
  const float* W_ih = (const float*)d_in[1];
  const float* W_hh = (const float*)d_in[2];
  const float* b_ih = (const float*)d_in[3];
  const float* b_hh = (const float*)d_in[4];
  const float* W_a = (const float*)d_in[5];
  const float* b_a = (const float*)d_in[6];
  char* ws = (char*)d_ws;
  float* out = (float*)d_out;

  (void)hipFuncSetAttribute(reinterpret_cast<const void*>(s2s_main),
                            hipFuncAttributeMaxDynamicSharedMemorySize, SMEM_BYTES);

  k0_init<<<1, TT, 0, stream>>>(ws);
  k1_hp<<<256, 256, 0, stream>>>(h, W_a, b_a, ws);
  k2_pack<<<1024, 256, 0, stream>>>(h, W_ih, W_hh, b_ih, b_hh, ws);
  s2s_main<<<NWG, TT, SMEM_BYTES, stream>>>(ws, out);
}

// Round 13
// 25236.200 us; speedup vs baseline: 1.1910x; 1.1910x over previous
//
#include <hip/hip_runtime.h>
#include <stdint.h>

#define NN 4096      // nodes / steps
#define DD 256       // hidden dim
#define NWG 64       // workgroups
#define TT 256       // threads per WG
#define ROWS 64      // NN/NWG rows per WG
#define GR 16        // gate rows per WG (1024/NWG)
#define NSTEPS 4096
#define GUARD (1u << 20)

typedef float f32x4 __attribute__((ext_vector_type(4)));

// ---------------- workspace layout (bytes) ---------------- (R8-proven)
#define OFF_HDR      0u          // 64 x 64B: {u32 tag, f32 ps, pad...}
#define OFF_QS       4096u       // 64 x 128B: lineA {tag,q0,q1,q2} @+0, lineB {tag,q3,-,-} @+64
#define OFF_SCAL     12288u      // [0]=maxHpNorm bits, [1]=ebBound bits
#define OFF_PR       12352u      // 64*256 f32 partial r-tilde
#define OFF_EB       77888u      // 4096 f32  (h @ b_a)
#define OFF_BPACK    94272u      // 1024 f32 packed bias
#define OFF_WPACK    98368u      // 1024*512 f32 packed gate weights (+2097152)
#define OFF_HPB      2195520u    // 4096*256 bf16 packed [wg][k4][row] (Hp) (+2097152)
#define OFF_HP2      4292672u    // paired-row h bf16: [wg][r2:32][col:256] uint (+2097152)
// total 6,389,824 B

// ---------------- LDS layout ----------------
#define S_HPL    0u        // 32768  uint2 [k4:64][row:64]
#define S_HP     32768u    // 32768  uint  [r2:32][col:256]
#define S_WL     65536u    // 33280  f32   [16][520] (padded stride vs bank conflicts)
#define S_QRL    98816u    // 2048   f32   [512] : q | r
#define S_PRL    100864u   // 4096   f32   [4][256] combine partials
#define S_RACC   104960u   // 1088   f32   publish staging
#define S_EL     106048u   // 1024   f32   [4][64]
#define S_PL     107072u   // 256    f32   [64]
#define S_GL     107328u   // 64     f32   [16]
#define S_CLS    107392u   // 16     f32   [4]
#define S_RED4   107408u   // 16
#define S_SL     107424u   // 16
#define S_EBL    107440u   // 256    f32   [64]
#define S_QL4    107696u   // 16     f32   [4]
#define SMEM_BYTES 107712

__device__ __forceinline__ float bf2f(unsigned short u) {
  return __uint_as_float(((unsigned)u) << 16);
}
__device__ __forceinline__ unsigned short f2bf(float f) {
  unsigned x = __float_as_uint(f);
  unsigned r = x + 0x7fffu + ((x >> 16) & 1u);
  return (unsigned short)(r >> 16);
}

// ---- coherent-bypass memory ops (sc0 sc1: skip L1/L2, device-coherent) ----
__device__ __forceinline__ f32x4 ld_v4(const void* p) {
  f32x4 v;
  asm volatile("global_load_dwordx4 %0, %1, off sc0 sc1\n\ts_waitcnt vmcnt(0)"
               : "=v"(v) : "v"(p) : "memory");
  return v;
}
__device__ __forceinline__ f32x4 ld_v4_async(const void* p) {
  f32x4 v;
  asm volatile("global_load_dwordx4 %0, %1, off sc0 sc1" : "=v"(v) : "v"(p) : "memory");
  return v;
}
__device__ __forceinline__ void st_v4(void* p, f32x4 v) {
  asm volatile("global_store_dwordx4 %0, %1, off sc0 sc1" :: "v"(p), "v"(v) : "memory");
}
__device__ __forceinline__ void vmdrain() {
  asm volatile("s_waitcnt vmcnt(0)" ::: "memory");
}
__device__ __forceinline__ void npause() { __builtin_amdgcn_s_sleep(1); }

// ---------------- K0: init dynamic state ----------------
__global__ void k0_init(char* ws) {
  int t = threadIdx.x;
  unsigned* u = (unsigned*)ws;
  float* f = (float*)ws;
  for (int i = t; i < 64; i += TT) {
    u[(OFF_HDR >> 2) + i * 16] = 0u;
    f[(OFF_HDR >> 2) + i * 16 + 1] = 1.0f / NWG;
  }
  for (int i = t; i < 64; i += TT) {
    u[(OFF_QS >> 2) + i * 32] = 0u;
    u[(OFF_QS >> 2) + i * 32 + 16] = 0u;
  }
  if (t == 0) { u[OFF_SCAL / 4] = 0u; u[OFF_SCAL / 4 + 1] = 0u; }
  for (int i = t; i < 64 * 256; i += TT) f[(OFF_PR >> 2) + i] = 0.f;
}

// ---------------- K1: Hp = h @ W_a (bf16, packed), eb = h @ b_a, bounds ----------------
__global__ __launch_bounds__(256) void k1_hp(const float* __restrict__ h,
                                             const float* __restrict__ W_a,
                                             const float* __restrict__ b_a,
                                             char* ws) {
  __shared__ float hL1[16][256];
  __shared__ float scr[16][256];
  __shared__ float redN[4][16];
  __shared__ float redE[4][16];
  const int t = threadIdx.x, b = blockIdx.x;
  const int i0 = b * 16;
  for (int i = t; i < 16 * 256; i += 256) hL1[i >> 8][i & 255] = h[i0 * 256 + i];
  __syncthreads();
  float acc[16];
#pragma unroll
  for (int ii = 0; ii < 16; ++ii) acc[ii] = 0.f;
  for (int j = 0; j < 256; ++j) {
    float wa = W_a[j * 256 + t];
#pragma unroll
    for (int ii = 0; ii < 16; ++ii) acc[ii] += hL1[ii][j] * wa;
  }
#pragma unroll
  for (int ii = 0; ii < 16; ++ii) scr[ii][t] = acc[ii];
  const int lane = t & 63, wv = t >> 6;
  const float ba = b_a[t];
  for (int ii = 0; ii < 16; ++ii) {
    float a2 = acc[ii] * acc[ii];
    float eb = hL1[ii][t] * ba;
    for (int m = 32; m; m >>= 1) { a2 += __shfl_xor(a2, m); eb += __shfl_xor(eb, m); }
    if (lane == 0) { redN[wv][ii] = a2; redE[wv][ii] = eb; }
  }
  __syncthreads();
  unsigned* scal = (unsigned*)(ws + OFF_SCAL);
  float* ebg = (float*)(ws + OFF_EB);
  if (t < 16) {
    float n2 = redN[0][t] + redN[1][t] + redN[2][t] + redN[3][t];
    float ebv = redE[0][t] + redE[1][t] + redE[2][t] + redE[3][t];
    ebg[i0 + t] = ebv;
    atomicMax(scal + 0, __float_as_uint(sqrtf(n2)));
    atomicMax(scal + 1, __float_as_uint(fabsf(ebv)));
  }
  uint2* hpB = (uint2*)(ws + OFF_HPB);
  const int wq = b >> 2, sub = b & 3;
  for (int idx = t; idx < 16 * 64; idx += 256) {
    int ii = idx >> 6, k4 = idx & 63;
    unsigned short u0 = f2bf(scr[ii][4 * k4 + 0]);
    unsigned short u1 = f2bf(scr[ii][4 * k4 + 1]);
    unsigned short u2 = f2bf(scr[ii][4 * k4 + 2]);
    unsigned short u3 = f2bf(scr[ii][4 * k4 + 3]);
    uint2 pv;
    pv.x = (unsigned)u0 | ((unsigned)u1 << 16);
    pv.y = (unsigned)u2 | ((unsigned)u3 << 16);
    int rl = sub * 16 + ii;
    hpB[wq * 4096 + k4 * 64 + rl] = pv;
  }
}

// ---------------- K2: pack paired h (bf16), fold gate weights/bias ----------------
__global__ void k2_pack(const float* __restrict__ h, const float* __restrict__ W_ih,
                        const float* __restrict__ W_hh, const float* __restrict__ b_ih,
                        const float* __restrict__ b_hh, char* ws) {
  unsigned* hp2 = (unsigned*)(ws + OFF_HP2);
  float* wpack = (float*)(ws + OFF_WPACK);
  float* bpack = (float*)(ws + OFF_BPACK);
  int idx0 = blockIdx.x * blockDim.x + threadIdx.x;
  int stride = gridDim.x * blockDim.x;
  for (int i = idx0; i < NN * DD / 2; i += stride) {
    int col = i & 255;
    int r2 = (i >> 8) & 31;
    int w = i >> 13;
    int row0 = (w * 64 + 2 * r2) * 256 + col;
    hp2[i] = (unsigned)f2bf(h[row0]) | ((unsigned)f2bf(h[row0 + 256]) << 16);
  }
  for (int i = idx0; i < 1024 * 512; i += stride) {
    int row = i >> 9, c = i & 511;
    int g = row >> 8, d = row & 255;
    int wq = d >> 2, dl = d & 3;
    float v = W_ih[row * 512 + c];
    if (c < 256) v += W_hh[row * 256 + c];
    wpack[(wq * GR + g * 4 + dl) * 512 + c] = v;
  }
  for (int i = idx0; i < 1024; i += stride) {
    int g = i >> 8, d = i & 255, wq = d >> 2, dl = d & 3;
    bpack[wq * GR + g * 4 + dl] = b_ih[i] + b_hh[i];
  }
}

// ---------------- main persistent kernel ----------------
__global__ __launch_bounds__(TT, 1) void s2s_main(char* __restrict__ ws,
                                                  float* __restrict__ out) {
  extern __shared__ char smem[];
  uint2* HpL = (uint2*)(smem + S_HPL);
  unsigned* hP = (unsigned*)(smem + S_HP);
  float* wL = (float*)(smem + S_WL);
  float* qrL = (float*)(smem + S_QRL);
  float* prL = (float*)(smem + S_PRL);
  float* rAcc = (float*)(smem + S_RACC);
  float* eL = (float*)(smem + S_EL);
  float* pL = (float*)(smem + S_PL);
  float* gL = (float*)(smem + S_GL);
  float* cLs = (float*)(smem + S_CLS);
  float* red4 = (float*)(smem + S_RED4);
  float* sL = (float*)(smem + S_SL);
  float* ebL = (float*)(smem + S_EBL);
  float* qL4 = (float*)(smem + S_QL4);

  const int w = blockIdx.x, tid = threadIdx.x;
  char* hdrBase = ws + OFF_HDR;
  char* qsBase = ws + OFF_QS;
  const unsigned* scal = (const unsigned*)(ws + OFF_SCAL);
  float* pr = (float*)(ws + OFF_PR);
  const float* ebg = (const float*)(ws + OFF_EB);
  const float* bpack = (const float*)(ws + OFF_BPACK);
  const float* wpack = (const float*)(ws + OFF_WPACK);
  const uint2* hpB = (const uint2*)(ws + OFF_HPB) + (size_t)w * 4096;
  const unsigned* hp2 = (const unsigned*)(ws + OFF_HP2) + (size_t)w * 8192;

  for (int i = tid; i < 4096; i += TT) HpL[i] = hpB[i];
  for (int i = tid; i < 8192; i += TT) hP[i] = hp2[i];
  for (int i = tid; i < 8192; i += TT) {
    int r = i >> 9, c = i & 511;
    wL[r * 520 + c] = wpack[(size_t)w * 8192 + i];
  }
  if (tid < 64) ebL[tid] = ebg[w * 64 + tid];
  if (tid < 4) cLs[tid] = 0.f;
  qrL[tid] = 0.f;
  qrL[256 + tid] = 0.f;
  const float maxHpN = __uint_as_float(scal[0]);
  const float ebB = __uint_as_float(scal[1]);
  __syncthreads();

  const int gr_lr = tid >> 4, gr_li = tid & 15;
  const float* wrow = wL + gr_lr * 520;
  const float brow = bpack[w * GR + gr_lr];
  const int wv4 = tid >> 6, l = tid & 63;
  float psW = 0.f;   // valid in tid 0 only
  float acc = 0.f;   // Wq @ q_{t-1}, carried from drain-shadow (q_{-1}=0)

  for (int t = 0; t < NSTEPS; ++t) {
    // ==== phase A: q_t = LSTM(q_{t-1}, r_{t-1}) ====
    // wait partials headers (tag >= t), grab ps from same 16B line (wave 0 only)
    if (tid < 64) {
      const char* hp = hdrBase + tid * 64;
      float psv;
      unsigned guard = 0;
      for (;;) {
        f32x4 hv = ld_v4(hp);
        if (__float_as_uint(hv.x) >= (unsigned)t || ++guard > GUARD) { psv = hv.y; break; }
        npause();
      }
      float s = psv;
#pragma unroll
      for (int m = 32; m; m >>= 1) s += __shfl_xor(s, m);
      if (tid == 0) sL[0] = fmaxf(s, 1e-35f);
    }
    __syncthreads();
    // combine partial r: wave wv4 sums 16 slices, lane l -> 4 cols (rotated by w)
    {
      f32x4 tv[16];
#pragma unroll
      for (int i = 0; i < 16; ++i) {
        int v = (wv4 * 16 + i + w) & 63;
        tv[i] = ld_v4_async(pr + v * 256 + (l << 2));
      }
      vmdrain();
      __builtin_amdgcn_sched_barrier(0);
      float rx = 0.f, ry = 0.f, rz = 0.f, rw = 0.f;
#pragma unroll
      for (int i = 0; i < 16; ++i) { rx += tv[i].x; ry += tv[i].y; rz += tv[i].z; rw += tv[i].w; }
      float* d = prL + wv4 * 256 + (l << 2);
      d[0] = rx; d[1] = ry; d[2] = rz; d[3] = rw;
    }
    __syncthreads();
    {
      float rsum = prL[tid] + prL[256 + tid] + prL[512 + tid] + prL[768 + tid];
      qrL[256 + tid] = rsum / sL[0];  // r_{t-1}
    }
    __syncthreads();
    // Wr @ r (Wq @ q_{t-1} already in carried acc from drain-shadow)
#pragma unroll
    for (int j = 4; j < 8; ++j) {
      int c0 = gr_li * 4 + j * 64;
      const float4 wv = *(const float4*)(wrow + c0);
      const float4 qv = *(const float4*)(qrL + c0);
      acc += wv.x * qv.x + wv.y * qv.y + wv.z * qv.z + wv.w * qv.w;
    }
    acc += __shfl_xor(acc, 8);
    acc += __shfl_xor(acc, 4);
    acc += __shfl_xor(acc, 2);
    acc += __shfl_xor(acc, 1);
    if (gr_li == 0) gL[gr_lr] = acc + brow;
    __syncthreads();
    if (tid < 4) {
      float gi = gL[tid], gf = gL[4 + tid], gg = gL[8 + tid], go = gL[12 + tid];
      float co = cLs[tid];
      float si = 1.f / (1.f + __expf(-gi));
      float sf = 1.f / (1.f + __expf(-gf));
      float so = 1.f / (1.f + __expf(-go));
      float cn = sf * co + si * tanhf(gg);
      cLs[tid] = cn;
      qL4[tid] = so * tanhf(cn);
    }
    // qL4 written by wave 0, read by wave 0 -> same-wave LDS order
    if (tid < 2) {
      float4 q4 = *(const float4*)qL4;
      f32x4 line;
      line.x = __uint_as_float((unsigned)(t + 1));
      if (tid == 0) { line.y = q4.x; line.z = q4.y; line.w = q4.z; }
      else          { line.y = q4.w; line.z = 0.f;  line.w = 0.f; }
      st_v4(qsBase + w * 128 + tid * 64, line);  // self-validating, no drain
    }

    // ==== phase B: e = Hp q + eb, partials ====
    // per-wave q poll: wave wv4 needs slices [16*wv4, 16*wv4+16)
    float nr = 0.f;
    if (l < 32) {
      const int w2 = (wv4 << 4) + (l >> 1);
      const char* qp = qsBase + w2 * 128 + (l & 1) * 64;
      const unsigned need = (unsigned)(t + 1);
      f32x4 qv = ld_v4(qp);               // fast path: no sleep
      unsigned guard = 0;
      while (__float_as_uint(qv.x) < need && ++guard <= GUARD) {
        npause();
        qv = ld_v4(qp);
      }
      if ((l & 1) == 0) {
        qrL[4 * w2] = qv.y; qrL[4 * w2 + 1] = qv.z; qrL[4 * w2 + 2] = qv.w;
        nr = qv.y * qv.y + qv.z * qv.z + qv.w * qv.w;
      } else {
        qrL[4 * w2 + 3] = qv.y;
        nr = qv.y * qv.y;
      }
    }
#pragma unroll
    for (int m = 1; m < 64; m <<= 1) nr += __shfl_xor(nr, m);
    if (l == 0) red4[wv4] = nr;
    // e partial on own quarter (qrL quarter written by this wave)
    f32x4 qk[16];
#pragma unroll
    for (int j = 0; j < 16; ++j)
      qk[j] = *(const f32x4*)(qrL + (wv4 << 6) + (j << 2));
    float eacc = 0.f;
#pragma unroll
    for (int j = 0; j < 16; ++j) {
      const uint2 hp = HpL[(((wv4 << 4) + j) << 6) + l];
      eacc += bf2f((unsigned short)(hp.x)) * qk[j].x +
              bf2f((unsigned short)(hp.x >> 16)) * qk[j].y +
              bf2f((unsigned short)(hp.y)) * qk[j].z +
              bf2f((unsigned short)(hp.y >> 16)) * qk[j].w;
    }
    eL[(wv4 << 6) + l] = eacc;
    __syncthreads();
    if (tid < 64) {
      const float qnorm = sqrtf(red4[0] + red4[1] + red4[2] + red4[3]);
      const float Mhat = 0.5f * maxHpN * qnorm + ebB;
      float e = eL[tid] + eL[64 + tid] + eL[128 + tid] + eL[192 + tid] + ebL[tid];
      float p = __expf(fminf(e - Mhat, 60.f));
      pL[tid] = p;
      float sv = p;
#pragma unroll
      for (int m = 32; m; m >>= 1) sv += __shfl_xor(sv, m);
      if (tid == 0) psW = sv;
    }
    __syncthreads();
    // r partial over 32 paired rows
    float r2 = 0.f;
#pragma unroll
    for (int r2i = 0; r2i < 32; ++r2i) {
      const unsigned hv = hP[(r2i << 8) + tid];
      r2 += pL[2 * r2i] * bf2f((unsigned short)hv) +
            pL[2 * r2i + 1] * bf2f((unsigned short)(hv >> 16));
    }
    rAcc[tid] = r2;
    __syncthreads();
    // wave 0 issues coalesced pr stores (no drain yet)
    if (tid < 64) {
      f32x4 pv;
      pv.x = rAcc[4 * tid]; pv.y = rAcc[4 * tid + 1];
      pv.z = rAcc[4 * tid + 2]; pv.w = rAcc[4 * tid + 3];
      st_v4(pr + (w << 8) + (tid << 2), pv);
    }
    // drain-shadow: next step's Wq @ q_t runs while store-acks are in flight
    {
      float accN = 0.f;
#pragma unroll
      for (int j = 0; j < 4; ++j) {
        int c0 = gr_li * 4 + j * 64;
        const float4 wv = *(const float4*)(wrow + c0);
        const float4 qv = *(const float4*)(qrL + c0);
        accN += wv.x * qv.x + wv.y * qv.y + wv.z * qv.z + wv.w * qv.w;
      }
      if (tid < 64) vmdrain();    // wave 0 drains its own partial stores
      __syncthreads();            // all waves see completion
      if (tid == 0) {
        f32x4 hv4;
        hv4.x = __uint_as_float((unsigned)(t + 1));
        hv4.y = psW; hv4.z = 0.f; hv4.w = 0.f;
        st_v4(hdrBase + w * 64, hv4);
      }
      acc = accN;
    }
  }

  // ==== epilogue: q_star = [q_final, r_final] (WG 0 only) ====
  if (w == 0) {
    if (tid < 64) {
      const char* hp = hdrBase + tid * 64;
      float psv;
      unsigned guard = 0;
      for (;;) {
        f32x4 hv = ld_v4(hp);
        if (__float_as_uint(hv.x) >= (unsigned)NSTEPS || ++guard > GUARD) { psv = hv.y; break; }
        npause();
      }
      float s = psv;
#pragma unroll
      for (int m = 32; m; m >>= 1) s += __shfl_xor(s, m);
      if (tid == 0) sL[0] = fmaxf(s, 1e-35f);
    }
    __syncthreads();
    {
      f32x4 tv[16];
#pragma unroll
      for (int i = 0; i < 16; ++i) {
        int v = (wv4 * 16 + i) & 63;
        tv[i] = ld_v4_async(pr + v * 256 + (l << 2));
      }
      vmdrain();
      __builtin_amdgcn_sched_barrier(0);
      float rx = 0.f, ry = 0.f, rz = 0.f, rw = 0.f;
#pragma unroll
      for (int i = 0; i < 16; ++i) { rx += tv[i].x; ry += tv[i].y; rz += tv[i].z; rw += tv[i].w; }
      float* d = prL + wv4 * 256 + (l << 2);
      d[0] = rx; d[1] = ry; d[2] = rz; d[3] = rw;
    }
    __syncthreads();
    float rsum = prL[tid] + prL[256 + tid] + prL[512 + tid] + prL[768 + tid];
    out[tid] = qrL[tid];            // q_final (phase B kept q in qrL)
    out[256 + tid] = rsum / sL[0];  // r_final
  }
}

extern "C" void kernel_launch(void* const* d_in, const int* in_sizes, int n_in,
                              void* d_out, int out_size, void* d_ws, size_t ws_size,
                              hipStream_t stream) {
  const float* h = (const float*)d_in[0];
  const float* W_ih = (const float*)d_in[1];
  const float* W_hh = (const float*)d_in[2];
  const float* b_ih = (const float*)d_in[3];
  const float* b_hh = (const float*)d_in[4];
  const float* W_a = (const float*)d_in[5];
  const float* b_a = (const float*)d_in[6];
  char* ws = (char*)d_ws;
  float* out = (float*)d_out;

  (void)hipFuncSetAttribute(reinterpret_cast<const void*>(s2s_main),
                            hipFuncAttributeMaxDynamicSharedMemorySize, SMEM_BYTES);

  k0_init<<<1, TT, 0, stream>>>(ws);
  k1_hp<<<256, 256, 0, stream>>>(h, W_a, b_a, ws);
  k2_pack<<<1024, 256, 0, stream>>>(h, W_ih, W_hh, b_ih, b_hh, ws);
  s2s_main<<<NWG, TT, SMEM_BYTES, stream>>>(ws, out);
}

// Round 14
// 24148.380 us; speedup vs baseline: 1.2446x; 1.0450x over previous
//
#include <hip/hip_runtime.h>
#include <stdint.h>

#define NN 4096      // nodes / steps
#define DD 256       // hidden dim
#define NWG 64       // workgroups
#define TT 256       // threads per WG
#define ROWS 64      // NN/NWG rows per WG
#define GR 16        // gate rows per WG (1024/NWG)
#define NSTEPS 4096
#define GUARD (1u << 20)

typedef float f32x4 __attribute__((ext_vector_type(4)));

// ---------------- workspace layout (bytes) ---------------- (R8-proven)
#define OFF_HDR      0u          // 64 x 64B: {u32 tag, f32 ps, pad...}
#define OFF_QS       4096u       // 64 x 128B: lineA {tag,q0,q1,q2} @+0, lineB {tag,q3,-,-} @+64
#define OFF_SCAL     12288u      // [0]=maxHpNorm bits, [1]=ebBound bits
#define OFF_PR       12352u      // 64*256 f32 partial r-tilde
#define OFF_EB       77888u      // 4096 f32  (h @ b_a)
#define OFF_BPACK    94272u      // 1024 f32 packed bias
#define OFF_WPACK    98368u      // 1024*512 f32 packed gate weights (+2097152)
#define OFF_HPB      2195520u    // 4096*256 bf16 packed [wg][k4][row] (Hp) (+2097152)
#define OFF_HP2      4292672u    // paired-row h bf16: [wg][r2:32][col:256] uint (+2097152)
// total 6,389,824 B

// ---------------- LDS layout ----------------
#define S_HPL    0u        // 32768  uint2 [k4:64][row:64]
#define S_HP     32768u    // 32768  uint  [r2:32][col:256]
#define S_WL     65536u    // 33280  f32   [16][520] (padded stride vs bank conflicts)
#define S_QRL    98816u    // 2048   f32   [512] : q | r
#define S_PRL    100864u   // 4096   f32   [4][256] combine partials
#define S_RACC   104960u   // 1088   f32   publish staging
#define S_EL     106048u   // 1024   f32   [4][64]
#define S_PL     107072u   // 256    f32   [64]
#define S_GL     107328u   // 64     f32   [16]
#define S_CLS    107392u   // 16     f32   [4]
#define S_RED4   107408u   // 16
#define S_SL     107424u   // 16
#define S_EBL    107440u   // 256    f32   [64]
#define S_QL4    107696u   // 16     f32   [4]
#define SMEM_BYTES 107712

__device__ __forceinline__ float bf2f(unsigned short u) {
  return __uint_as_float(((unsigned)u) << 16);
}
__device__ __forceinline__ unsigned short f2bf(float f) {
  unsigned x = __float_as_uint(f);
  unsigned r = x + 0x7fffu + ((x >> 16) & 1u);
  return (unsigned short)(r >> 16);
}

// ---- coherent-bypass memory ops (sc0 sc1: skip L1/L2, device-coherent) ----
__device__ __forceinline__ f32x4 ld_v4(const void* p) {
  f32x4 v;
  asm volatile("global_load_dwordx4 %0, %1, off sc0 sc1\n\ts_waitcnt vmcnt(0)"
               : "=v"(v) : "v"(p) : "memory");
  return v;
}
__device__ __forceinline__ f32x4 ld_v4_async(const void* p) {
  f32x4 v;
  asm volatile("global_load_dwordx4 %0, %1, off sc0 sc1" : "=v"(v) : "v"(p) : "memory");
  return v;
}
__device__ __forceinline__ void st_v4(void* p, f32x4 v) {
  asm volatile("global_store_dwordx4 %0, %1, off sc0 sc1" :: "v"(p), "v"(v) : "memory");
}
__device__ __forceinline__ void vmdrain() {
  asm volatile("s_waitcnt vmcnt(0)" ::: "memory");
}
__device__ __forceinline__ void npause() { __builtin_amdgcn_s_sleep(1); }

// ---------------- K0: init dynamic state ----------------
__global__ void k0_init(char* ws) {
  int t = threadIdx.x;
  unsigned* u = (unsigned*)ws;
  float* f = (float*)ws;
  for (int i = t; i < 64; i += TT) {
    u[(OFF_HDR >> 2) + i * 16] = 0u;
    f[(OFF_HDR >> 2) + i * 16 + 1] = 1.0f / NWG;
  }
  for (int i = t; i < 64; i += TT) {
    u[(OFF_QS >> 2) + i * 32] = 0u;
    u[(OFF_QS >> 2) + i * 32 + 16] = 0u;
  }
  if (t == 0) { u[OFF_SCAL / 4] = 0u; u[OFF_SCAL / 4 + 1] = 0u; }
  for (int i = t; i < 64 * 256; i += TT) f[(OFF_PR >> 2) + i] = 0.f;
}

// ---------------- K1: Hp = h @ W_a (bf16, packed), eb = h @ b_a, bounds ----------------
__global__ __launch_bounds__(256) void k1_hp(const float* __restrict__ h,
                                             const float* __restrict__ W_a,
                                             const float* __restrict__ b_a,
                                             char* ws) {
  __shared__ float hL1[16][256];
  __shared__ float scr[16][256];
  __shared__ float redN[4][16];
  __shared__ float redE[4][16];
  const int t = threadIdx.x, b = blockIdx.x;
  const int i0 = b * 16;
  for (int i = t; i < 16 * 256; i += 256) hL1[i >> 8][i & 255] = h[i0 * 256 + i];
  __syncthreads();
  float acc[16];
#pragma unroll
  for (int ii = 0; ii < 16; ++ii) acc[ii] = 0.f;
  for (int j = 0; j < 256; ++j) {
    float wa = W_a[j * 256 + t];
#pragma unroll
    for (int ii = 0; ii < 16; ++ii) acc[ii] += hL1[ii][j] * wa;
  }
#pragma unroll
  for (int ii = 0; ii < 16; ++ii) scr[ii][t] = acc[ii];
  const int lane = t & 63, wv = t >> 6;
  const float ba = b_a[t];
  for (int ii = 0; ii < 16; ++ii) {
    float a2 = acc[ii] * acc[ii];
    float eb = hL1[ii][t] * ba;
    for (int m = 32; m; m >>= 1) { a2 += __shfl_xor(a2, m); eb += __shfl_xor(eb, m); }
    if (lane == 0) { redN[wv][ii] = a2; redE[wv][ii] = eb; }
  }
  __syncthreads();
  unsigned* scal = (unsigned*)(ws + OFF_SCAL);
  float* ebg = (float*)(ws + OFF_EB);
  if (t < 16) {
    float n2 = redN[0][t] + redN[1][t] + redN[2][t] + redN[3][t];
    float ebv = redE[0][t] + redE[1][t] + redE[2][t] + redE[3][t];
    ebg[i0 + t] = ebv;
    atomicMax(scal + 0, __float_as_uint(sqrtf(n2)));
    atomicMax(scal + 1, __float_as_uint(fabsf(ebv)));
  }
  uint2* hpB = (uint2*)(ws + OFF_HPB);
  const int wq = b >> 2, sub = b & 3;
  for (int idx = t; idx < 16 * 64; idx += 256) {
    int ii = idx >> 6, k4 = idx & 63;
    unsigned short u0 = f2bf(scr[ii][4 * k4 + 0]);
    unsigned short u1 = f2bf(scr[ii][4 * k4 + 1]);
    unsigned short u2 = f2bf(scr[ii][4 * k4 + 2]);
    unsigned short u3 = f2bf(scr[ii][4 * k4 + 3]);
    uint2 pv;
    pv.x = (unsigned)u0 | ((unsigned)u1 << 16);
    pv.y = (unsigned)u2 | ((unsigned)u3 << 16);
    int rl = sub * 16 + ii;
    hpB[wq * 4096 + k4 * 64 + rl] = pv;
  }
}

// ---------------- K2: pack paired h (bf16), fold gate weights/bias ----------------
__global__ void k2_pack(const float* __restrict__ h, const float* __restrict__ W_ih,
                        const float* __restrict__ W_hh, const float* __restrict__ b_ih,
                        const float* __restrict__ b_hh, char* ws) {
  unsigned* hp2 = (unsigned*)(ws + OFF_HP2);
  float* wpack = (float*)(ws + OFF_WPACK);
  float* bpack = (float*)(ws + OFF_BPACK);
  int idx0 = blockIdx.x * blockDim.x + threadIdx.x;
  int stride = gridDim.x * blockDim.x;
  for (int i = idx0; i < NN * DD / 2; i += stride) {
    int col = i & 255;
    int r2 = (i >> 8) & 31;
    int w = i >> 13;
    int row0 = (w * 64 + 2 * r2) * 256 + col;
    hp2[i] = (unsigned)f2bf(h[row0]) | ((unsigned)f2bf(h[row0 + 256]) << 16);
  }
  for (int i = idx0; i < 1024 * 512; i += stride) {
    int row = i >> 9, c = i & 511;
    int g = row >> 8, d = row & 255;
    int wq = d >> 2, dl = d & 3;
    float v = W_ih[row * 512 + c];
    if (c < 256) v += W_hh[row * 256 + c];
    wpack[(wq * GR + g * 4 + dl) * 512 + c] = v;
  }
  for (int i = idx0; i < 1024; i += stride) {
    int g = i >> 8, d = i & 255, wq = d >> 2, dl = d & 3;
    bpack[wq * GR + g * 4 + dl] = b_ih[i] + b_hh[i];
  }
}

// ---------------- main persistent kernel ----------------
__global__ __launch_bounds__(TT, 1) void s2s_main(char* __restrict__ ws,
                                                  float* __restrict__ out) {
  extern __shared__ char smem[];
  uint2* HpL = (uint2*)(smem + S_HPL);
  unsigned* hP = (unsigned*)(smem + S_HP);
  float* wL = (float*)(smem + S_WL);
  float* qrL = (float*)(smem + S_QRL);
  float* prL = (float*)(smem + S_PRL);
  float* rAcc = (float*)(smem + S_RACC);
  float* eL = (float*)(smem + S_EL);
  float* pL = (float*)(smem + S_PL);
  float* gL = (float*)(smem + S_GL);
  float* cLs = (float*)(smem + S_CLS);
  float* red4 = (float*)(smem + S_RED4);
  float* ebL = (float*)(smem + S_EBL);
  float* qL4 = (float*)(smem + S_QL4);

  const int w = blockIdx.x, tid = threadIdx.x;
  char* hdrBase = ws + OFF_HDR;
  char* qsBase = ws + OFF_QS;
  const unsigned* scal = (const unsigned*)(ws + OFF_SCAL);
  float* pr = (float*)(ws + OFF_PR);
  const float* ebg = (const float*)(ws + OFF_EB);
  const float* bpack = (const float*)(ws + OFF_BPACK);
  const float* wpack = (const float*)(ws + OFF_WPACK);
  const uint2* hpB = (const uint2*)(ws + OFF_HPB) + (size_t)w * 4096;
  const unsigned* hp2 = (const unsigned*)(ws + OFF_HP2) + (size_t)w * 8192;

  for (int i = tid; i < 4096; i += TT) HpL[i] = hpB[i];
  for (int i = tid; i < 8192; i += TT) hP[i] = hp2[i];
  for (int i = tid; i < 8192; i += TT) {
    int r = i >> 9, c = i & 511;
    wL[r * 520 + c] = wpack[(size_t)w * 8192 + i];
  }
  if (tid < 64) ebL[tid] = ebg[w * 64 + tid];
  if (tid < 4) cLs[tid] = 0.f;
  qrL[tid] = 0.f;
  qrL[256 + tid] = 0.f;
  const float maxHpN = __uint_as_float(scal[0]);
  const float ebB = __uint_as_float(scal[1]);
  __syncthreads();

  const int gr_lr = tid >> 4, gr_li = tid & 15;
  const float* wrow = wL + gr_lr * 520;
  const float brow = bpack[w * GR + gr_lr];
  const int wv4 = tid >> 6, l = tid & 63;
  float psW = 0.f;   // valid in tid 0 only
  float acc = 0.f;   // Wq @ q_{t-1}, carried from drain-shadow (q_{-1}=0)

  for (int t = 0; t < NSTEPS; ++t) {
    // ==== phase A: q_t = LSTM(q_{t-1}, r_{t-1}) ====
    // per-wave-group header poll: wave wv4 owns slices {(wv4*16+i+w)&63}
    {
      float psg = 0.f;
      if (l < 16) {
        const int sidx = (wv4 * 16 + l + w) & 63;
        const char* hp = hdrBase + sidx * 64;
        unsigned guard = 0;
        for (;;) {
          f32x4 hv = ld_v4(hp);
          if (__float_as_uint(hv.x) >= (unsigned)t || ++guard > GUARD) { psg = hv.y; break; }
          npause();
        }
      }
      // reduce ps over lanes 0..15 (xor masks stay within 16-lane group)
      psg += __shfl_xor(psg, 8);
      psg += __shfl_xor(psg, 4);
      psg += __shfl_xor(psg, 2);
      psg += __shfl_xor(psg, 1);
      if (l == 0) red4[wv4] = psg;
    }
    // bulk read immediately — this wave verified its own 16 slices (no barrier)
    {
      f32x4 tv[16];
#pragma unroll
      for (int i = 0; i < 16; ++i) {
        int v = (wv4 * 16 + i + w) & 63;
        tv[i] = ld_v4_async(pr + v * 256 + (l << 2));
      }
      vmdrain();
      __builtin_amdgcn_sched_barrier(0);
      float rx = 0.f, ry = 0.f, rz = 0.f, rw = 0.f;
#pragma unroll
      for (int i = 0; i < 16; ++i) { rx += tv[i].x; ry += tv[i].y; rz += tv[i].z; rw += tv[i].w; }
      float* d = prL + wv4 * 256 + (l << 2);
      d[0] = rx; d[1] = ry; d[2] = rz; d[3] = rw;
    }
    __syncthreads();
    {
      float pstot = fmaxf(red4[0] + red4[1] + red4[2] + red4[3], 1e-35f);
      float rsum = prL[tid] + prL[256 + tid] + prL[512 + tid] + prL[768 + tid];
      qrL[256 + tid] = rsum / pstot;  // r_{t-1}
    }
    __syncthreads();
    // Wr @ r (Wq @ q_{t-1} already in carried acc from drain-shadow)
#pragma unroll
    for (int j = 4; j < 8; ++j) {
      int c0 = gr_li * 4 + j * 64;
      const float4 wv = *(const float4*)(wrow + c0);
      const float4 qv = *(const float4*)(qrL + c0);
      acc += wv.x * qv.x + wv.y * qv.y + wv.z * qv.z + wv.w * qv.w;
    }
    acc += __shfl_xor(acc, 8);
    acc += __shfl_xor(acc, 4);
    acc += __shfl_xor(acc, 2);
    acc += __shfl_xor(acc, 1);
    if (gr_li == 0) gL[gr_lr] = acc + brow;
    __syncthreads();
    if (tid < 4) {
      float gi = gL[tid], gf = gL[4 + tid], gg = gL[8 + tid], go = gL[12 + tid];
      float co = cLs[tid];
      float si = 1.f / (1.f + __expf(-gi));
      float sf = 1.f / (1.f + __expf(-gf));
      float so = 1.f / (1.f + __expf(-go));
      float cn = sf * co + si * tanhf(gg);
      cLs[tid] = cn;
      qL4[tid] = so * tanhf(cn);
    }
    // qL4 written by wave 0, read by wave 0 -> same-wave LDS order
    if (tid < 2) {
      float4 q4 = *(const float4*)qL4;
      f32x4 line;
      line.x = __uint_as_float((unsigned)(t + 1));
      if (tid == 0) { line.y = q4.x; line.z = q4.y; line.w = q4.z; }
      else          { line.y = q4.w; line.z = 0.f;  line.w = 0.f; }
      st_v4(qsBase + w * 128 + tid * 64, line);  // self-validating, no drain
    }

    // ==== phase B: e = Hp q + eb, partials ====
    // per-wave q poll: wave wv4 needs slices [16*wv4, 16*wv4+16)
    float nr = 0.f;
    if (l < 32) {
      const int w2 = (wv4 << 4) + (l >> 1);
      const char* qp = qsBase + w2 * 128 + (l & 1) * 64;
      const unsigned need = (unsigned)(t + 1);
      f32x4 qv = ld_v4(qp);               // fast path: no sleep
      unsigned guard = 0;
      while (__float_as_uint(qv.x) < need && ++guard <= GUARD) {
        npause();
        qv = ld_v4(qp);
      }
      if ((l & 1) == 0) {
        qrL[4 * w2] = qv.y; qrL[4 * w2 + 1] = qv.z; qrL[4 * w2 + 2] = qv.w;
        nr = qv.y * qv.y + qv.z * qv.z + qv.w * qv.w;
      } else {
        qrL[4 * w2 + 3] = qv.y;
        nr = qv.y * qv.y;
      }
    }
#pragma unroll
    for (int m = 1; m < 64; m <<= 1) nr += __shfl_xor(nr, m);
    if (l == 0) red4[wv4] = nr;
    // e partial on own quarter (qrL quarter written by this wave)
    f32x4 qk[16];
#pragma unroll
    for (int j = 0; j < 16; ++j)
      qk[j] = *(const f32x4*)(qrL + (wv4 << 6) + (j << 2));
    float eacc = 0.f;
#pragma unroll
    for (int j = 0; j < 16; ++j) {
      const uint2 hp = HpL[(((wv4 << 4) + j) << 6) + l];
      eacc += bf2f((unsigned short)(hp.x)) * qk[j].x +
              bf2f((unsigned short)(hp.x >> 16)) * qk[j].y +
              bf2f((unsigned short)(hp.y)) * qk[j].z +
              bf2f((unsigned short)(hp.y >> 16)) * qk[j].w;
    }
    eL[(wv4 << 6) + l] = eacc;
    __syncthreads();
    if (tid < 64) {
      const float qnorm = sqrtf(red4[0] + red4[1] + red4[2] + red4[3]);
      const float Mhat = 0.5f * maxHpN * qnorm + ebB;
      float e = eL[tid] + eL[64 + tid] + eL[128 + tid] + eL[192 + tid] + ebL[tid];
      float p = __expf(fminf(e - Mhat, 60.f));
      pL[tid] = p;
      float sv = p;
#pragma unroll
      for (int m = 32; m; m >>= 1) sv += __shfl_xor(sv, m);
      if (tid == 0) psW = sv;
    }
    __syncthreads();
    // r partial over 32 paired rows
    float r2 = 0.f;
#pragma unroll
    for (int r2i = 0; r2i < 32; ++r2i) {
      const unsigned hv = hP[(r2i << 8) + tid];
      r2 += pL[2 * r2i] * bf2f((unsigned short)hv) +
            pL[2 * r2i + 1] * bf2f((unsigned short)(hv >> 16));
    }
    rAcc[tid] = r2;
    __syncthreads();
    // wave 0 issues coalesced pr stores (no drain yet)
    if (tid < 64) {
      f32x4 pv;
      pv.x = rAcc[4 * tid]; pv.y = rAcc[4 * tid + 1];
      pv.z = rAcc[4 * tid + 2]; pv.w = rAcc[4 * tid + 3];
      st_v4(pr + (w << 8) + (tid << 2), pv);
    }
    // drain-shadow: next step's Wq @ q_t runs while store-acks are in flight
    {
      float accN = 0.f;
#pragma unroll
      for (int j = 0; j < 4; ++j) {
        int c0 = gr_li * 4 + j * 64;
        const float4 wv = *(const float4*)(wrow + c0);
        const float4 qv = *(const float4*)(qrL + c0);
        accN += wv.x * qv.x + wv.y * qv.y + wv.z * qv.z + wv.w * qv.w;
      }
      if (tid < 64) vmdrain();    // wave 0 drains its own partial stores
      __syncthreads();            // all waves see completion
      if (tid == 0) {
        f32x4 hv4;
        hv4.x = __uint_as_float((unsigned)(t + 1));
        hv4.y = psW; hv4.z = 0.f; hv4.w = 0.f;
        st_v4(hdrBase + w * 64, hv4);
      }
      acc = accN;
    }
  }

  // ==== epilogue: q_star = [q_final, r_final] (WG 0 only) ====
  if (w == 0) {
    {
      float psg = 0.f;
      if (l < 16) {
        const int sidx = (wv4 * 16 + l) & 63;
        const char* hp = hdrBase + sidx * 64;
        unsigned guard = 0;
        for (;;) {
          f32x4 hv = ld_v4(hp);
          if (__float_as_uint(hv.x) >= (unsigned)NSTEPS || ++guard > GUARD) { psg = hv.y; break; }
          npause();
        }
      }
      psg += __shfl_xor(psg, 8);
      psg += __shfl_xor(psg, 4);
      psg += __shfl_xor(psg, 2);
      psg += __shfl_xor(psg, 1);
      if (l == 0) red4[wv4] = psg;
    }
    {
      f32x4 tv[16];
#pragma unroll
      for (int i = 0; i < 16; ++i) {
        int v = (wv4 * 16 + i) & 63;
        tv[i] = ld_v4_async(pr + v * 256 + (l << 2));
      }
      vmdrain();
      __builtin_amdgcn_sched_barrier(0);
      float rx = 0.f, ry = 0.f, rz = 0.f, rw = 0.f;
#pragma unroll
      for (int i = 0; i < 16; ++i) { rx += tv[i].x; ry += tv[i].y; rz += tv[i].z; rw += tv[i].w; }
      float* d = prL + wv4 * 256 + (l << 2);
      d[0] = rx; d[1] = ry; d[2] = rz; d[3] = rw;
    }
    __syncthreads();
    float pstot = fmaxf(red4[0] + red4[1] + red4[2] + red4[3], 1e-35f);
    float rsum = prL[tid] + prL[256 + tid] + prL[512 + tid] + prL[768 + tid];
    out[tid] = qrL[tid];            // q_final (phase B kept q in qrL)
    out[256 + tid] = rsum / pstot;  // r_final
  }
}

extern "C" void kernel_launch(void* const* d_in, const int* in_sizes, int n_in,
                              void* d_out, int out_size, void* d_ws, size_t ws_size,
                              hipStream_t stream) {
  const float* h = (const float*)d_in[0];
  const float* W_ih = (const float*)d_in[1];
  const float* W_hh = (const float*)d_in[2];
  const float* b_ih = (const float*)d_in[3];
  const float* b_hh = (const float*)d_in[4];
  const float* W_a = (const float*)d_in[5];
  const float* b_a = (const float*)d_in[6];
  char* ws = (char*)d_ws;
  float* out = (float*)d_out;

  (void)hipFuncSetAttribute(reinterpret_cast<const void*>(s2s_main),
                            hipFuncAttributeMaxDynamicSharedMemorySize, SMEM_BYTES);

  k0_init<<<1, TT, 0, stream>>>(ws);
  k1_hp<<<256, 256, 0, stream>>>(h, W_a, b_a, ws);
  k2_pack<<<1024, 256, 0, stream>>>(h, W_ih, W_hh, b_ih, b_hh, ws);
  s2s_main<<<NWG, TT, SMEM_BYTES, stream>>>(ws, out);
}